// Round 9
// baseline (1318.412 us; speedup 1.0000x reference)
//
#include <hip/hip_runtime.h>
#include <math.h>
#include <stdint.h>

#define Bb 64
#define Nn 4096
#define Uu 64
#define RL 4224                         // 64*66 feature columns
#define NU (Nn*Uu)
#define UNITS 528                       // RL/8 column units
#define USZ 32768                       // ushorts per unit slice (4096 rows * 8 cols)
#define MATSZ ((size_t)UNITS*USZ)       // elements per feature matrix (= 4096*4224)
#define ELLW 112                        // ELL row capacity (avg nnz ~42)
#define XSTR 360                        // K-stride in gemm LDS (pad of 352)

typedef __attribute__((ext_vector_type(8))) short short8;
typedef __attribute__((ext_vector_type(4))) float f32x4;
typedef __attribute__((ext_vector_type(2))) float f32x2;
typedef unsigned int uint;
typedef unsigned short ushort;

__device__ inline uint f2bf(float f){ uint u=__float_as_uint(f); u += 0x7fffu + ((u>>16)&1u); return u>>16; }
__device__ inline uint pack2(float a,float b){
  uint ua=__float_as_uint(a); ua+=0x7fffu+((ua>>16)&1u);
  uint ub=__float_as_uint(b); ub+=0x7fffu+((ub>>16)&1u);
  return (ua>>16)|(ub&0xffff0000u);
}
__device__ inline float blo(uint u){ return __uint_as_float(u << 16); }
__device__ inline float bhi(uint u){ return __uint_as_float(u & 0xffff0000u); }

// ---------------- ELL extraction (row-major, raw counts, no pad) ----------------
__global__ __launch_bounds__(256) void k_fill(const float* __restrict__ sup,
                                              uint* __restrict__ pkv, int* __restrict__ rcnt) {
  const int lane = threadIdx.x & 63;
  const int row = blockIdx.x * 4 + (threadIdx.x >> 6);
  const float* rp = sup + (size_t)row * Nn;
  uint* outp = pkv + (size_t)row * ELLW;
  const unsigned long long lt = (1ull << lane) - 1ull;
  int off = 0;
  for (int j0 = 0; j0 < Nn; j0 += 64) {
    float v = rp[j0 + lane];
    unsigned long long m = __ballot(v != 0.0f);
    if (v != 0.0f) {
      int pos = off + (int)__popcll(m & lt);
      if (pos < ELLW) outp[pos] = (f2bf(v) << 16) | (uint)(j0 + lane);
    }
    off += (int)__popcll(m);
  }
  if (lane == 0) rcnt[row] = (off > ELLW) ? ELLW : off;
}

// ---------------- ELL transpose -> column-major pT[i][8192] ----------------
// Wave e-loads in the walk become 256B coalesced (was 64 cache lines per wave-load).
__global__ __launch_bounds__(256) void k_tr(const uint* __restrict__ pkv, uint* __restrict__ pT) {
  __shared__ uint tile[64*113];                  // stride 113: odd vs 32 banks
  const int g = blockIdx.x, t = threadIdx.x;     // 128 blocks x 64 rows
  const uint* src = pkv + (size_t)g * 64 * ELLW;
  for (int idx = t; idx < 64*ELLW; idx += 256) {
    const int r = idx / ELLW, i = idx - r*ELLW;
    tile[r*113 + i] = src[idx];
  }
  __syncthreads();
  for (int idx = t; idx < 64*ELLW; idx += 256) {
    const int i = idx >> 6, r = idx & 63;
    pT[(size_t)i*8192 + g*64 + r] = tile[r*113 + i];
  }
}

// ---------------- x0 = [inputs | hx] bf16 in [unit][row][8] ----------------
__global__ __launch_bounds__(256) void k_bx0(const float* __restrict__ inp, const float* __restrict__ hx,
                                             ushort* __restrict__ x0) {
  const int u = blockIdx.x, n = blockIdx.y*256 + threadIdx.x;
  ushort vals[8];
  #pragma unroll
  for (int j = 0; j < 8; ++j) {
    const int q = u*8 + j, b = q/66, f = q - b*66;
    const float v = (f < 2) ? inp[(size_t)b*(Nn*2) + (size_t)n*2 + f]
                            : hx[(size_t)b*NU + (size_t)n*Uu + (f-2)];
    vals[j] = (ushort)f2bf(v);
  }
  *(uint4*)&x0[(size_t)u*USZ + (size_t)n*8] = *(uint4*)vals;
}

// ---------------- one nnz: ds_read_b128 + 4 packed FMAs ----------------
__device__ __forceinline__ void step1(const uint e, const char* __restrict__ slb,
                                      f32x2& a01, f32x2& a23, f32x2& a45, f32x2& a67) {
  const uint4 w = *(const uint4*)(slb + ((e << 4) & 0xffff0u));
  const float bb = bhi(e);
  const f32x2 bv = {bb, bb};
  a01 += bv * (f32x2){blo(w.x), bhi(w.x)};
  a23 += bv * (f32x2){blo(w.y), bhi(w.y)};
  a45 += bv * (f32x2){blo(w.z), bhi(w.z)};
  a67 += bv * (f32x2){blo(w.w), bhi(w.w)};
}

// ---------------- SpMM: y = A@x (PASS2: y = 2*A@x - xsub) ----------------
// [unit][row][8] layout: slab stage contiguous 64KB, stores/xsub coalesced (lane r ->
// 16B at row r). Column-ELL walk: 1 entry/lane/iter, coalesced e-load, ptr-bumped.
// 64KB slab -> 2 blocks/CU, 8 waves/SIMD. PASS1 stages x once, walks both supports.
template<bool PASS2>
__global__ __launch_bounds__(1024, 8) void k_spmm(const ushort* __restrict__ xin,
                                                  const ushort* __restrict__ xsub,
                                                  ushort* __restrict__ yout,
                                                  const int* __restrict__ rcnt,
                                                  const uint* __restrict__ pT) {
  __shared__ ushort slab[4096*8];                        // 64 KiB, 16B rows
  const char* slb = (const char*)slab;
  const int t = threadIdx.x, b = blockIdx.x;
  #pragma unroll 1
  for (int task = 0; task < 2; ++task) {
    int unit, r0, nr;
    if (task == 0) { unit = ((b & 7) << 6) + (b >> 3); r0 = 0; nr = 4096; }
    else           { unit = 512 + (b >> 5); r0 = (b & 31) * 128; nr = 128; }
    const size_t ub = (size_t)unit * USZ;
    #pragma unroll 1
    for (int s = 0; s < 2; ++s) {
      if (PASS2 || s == 0) {                             // pass1 shares the x slab
        if (task | s) __syncthreads();                   // walkers done before restage
        const ushort* src = xin + (PASS2 ? (size_t)s * MATSZ : (size_t)0) + ub;
        #pragma unroll
        for (int it = 0; it < 4; ++it) {
          const int j = it * 1024 + t;
          *(uint4*)&slab[j * 8] = *(const uint4*)&src[j * 8];
        }
        __syncthreads();
      }
      const int sb = s << 12;
      ushort* yo = yout + (size_t)s * MATSZ + ub;
      for (int r = r0 + t; r < r0 + nr; r += 1024) {     // 1 lane per output row
        const int c = rcnt[sb + r];
        const uint* pp = pT + sb + r;
        f32x2 a01={0.f,0.f}, a23={0.f,0.f}, a45={0.f,0.f}, a67={0.f,0.f};
        uint e = *pp;
        for (int i = 1; i < c; ++i) {                    // prefetch next, process current
          pp += 8192;
          const uint en = *pp;
          step1(e, slb, a01, a23, a45, a67);
          e = en;
        }
        step1(e, slb, a01, a23, a45, a67);
        uint4 o;
        if (PASS2) {
          const uint4 xv = *(const uint4*)&xsub[ub + (size_t)r*8];
          o.x = pack2(2.f*a01.x - blo(xv.x), 2.f*a01.y - bhi(xv.x));
          o.y = pack2(2.f*a23.x - blo(xv.y), 2.f*a23.y - bhi(xv.y));
          o.z = pack2(2.f*a45.x - blo(xv.z), 2.f*a45.y - bhi(xv.z));
          o.w = pack2(2.f*a67.x - blo(xv.w), 2.f*a67.y - bhi(xv.w));
        } else {
          o.x = pack2(a01.x, a01.y); o.y = pack2(a23.x, a23.y);
          o.z = pack2(a45.x, a45.y); o.w = pack2(a67.x, a67.y);
        }
        *(uint4*)&yo[(size_t)r*8] = o;
      }
    }
  }
}

// ---------------- W pre-pack into MFMA B-fragment order (bf16) ----------------
__global__ __launch_bounds__(256) void k_wpack(const float* __restrict__ W1, const float* __restrict__ W2,
                                               ushort* __restrict__ Wp1, ushort* __restrict__ Wp2) {
  const int tid = blockIdx.x*256 + threadIdx.x;
  const int i = tid & 7, l = (tid >> 3) & 63;
  if (tid < 45056) {
    const int g = tid >> 9, tt = g / 11, kk = g % 11;
    const int r = kk*32 + (l>>4)*8 + i, c = tt*16 + (l & 15);
    Wp1[tid] = (r < 330) ? (ushort)f2bf(W1[(size_t)r*128 + c]) : (ushort)0;
  } else {
    const int t2 = tid - 45056;
    const int g = t2 >> 9, tt = g / 11, kk = g % 11;
    const int r = kk*32 + (l>>4)*8 + i, c = tt*16 + (l & 15);
    Wp2[t2] = (r < 330) ? (ushort)f2bf(W2[(size_t)r*64 + c]) : (ushort)0;
  }
}

// ---------------- gemm LDS staging from [unit][row][8] layout ----------------
__device__ __forceinline__ void stage_xs(ushort* __restrict__ Xs,
                                         const ushort* __restrict__ x0, const ushort* __restrict__ y1,
                                         const ushort* __restrict__ y2, const int n, const int t) {
  for (int q = t; q < 64*XSTR/4; q += 256) ((unsigned long long*)Xs)[q] = 0ull;
  __syncthreads();
  #pragma unroll 1
  for (int m = 0; m < 5; ++m) {
    const ushort* mp;
    if (m == 0) mp = x0; else { mp = (m & 1) ? y1 : y2; if (m >= 3) mp += MATSZ; }
    for (int u = t; u < UNITS; u += 256) {
      const uint4 w = *(const uint4*)&mp[(size_t)u*USZ + (size_t)n*8];
      const ushort* wv = (const ushort*)&w;
      #pragma unroll
      for (int j = 0; j < 8; ++j) {
        const int q = u*8 + j, bq = q/66, f = q - bq*66;
        Xs[bq*XSTR + f*5 + m] = wv[j];
      }
    }
  }
  __syncthreads();
}

// ---------------- gconv1 output GEMM (MFMA), fused sigmoid + r*hx + u ----------------
__global__ __launch_bounds__(256) void k_gemm1(const ushort* __restrict__ x0, const ushort* __restrict__ y1,
                                               const ushort* __restrict__ y2, const ushort* __restrict__ Wp,
                                               const float* __restrict__ bias, const float* __restrict__ hx,
                                               ushort* __restrict__ x0w, ushort* __restrict__ ubuf) {
  __shared__ ushort Xs[64*XSTR];
  const int n = blockIdx.x, t = threadIdx.x;
  stage_xs(Xs, x0, y1, y2, n, t);
  const int w = t >> 6, l = t & 63;
  const int b0 = w * 16;
  f32x4 acc[8];
  for (int i = 0; i < 8; ++i) acc[i] = (f32x4){0.f,0.f,0.f,0.f};
  const int arow = b0 + (l & 15), koff0 = (l >> 4) * 8;
  for (int kk = 0; kk < 11; ++kk) {
    const short8 af = *(const short8*)&Xs[arow*XSTR + kk*32 + koff0];
    #pragma unroll
    for (int tt = 0; tt < 8; ++tt) {
      const short8 bf = *(const short8*)&Wp[(((size_t)tt*11 + kk)*64 + l)*8];
      acc[tt] = __builtin_amdgcn_mfma_f32_16x16x32_bf16(af, bf, acc[tt], 0, 0, 0);
    }
  }
  const int rg = (l >> 4) * 4;
  #pragma unroll
  for (int tt = 0; tt < 8; ++tt) {
    const int o = tt*16 + (l & 15);
    const float bs = bias[o];
    #pragma unroll
    for (int r = 0; r < 4; ++r) {
      const int b = b0 + rg + r;
      const float v = acc[tt][r] + bs;
      const float sg = 1.0f / (1.0f + __expf(-v));
      if (o < Uu) {
        const float h = hx[(size_t)b*NU + (size_t)n*Uu + o];
        const int q = b*66 + 2 + o;
        x0w[(size_t)(q>>3)*USZ + (size_t)n*8 + (q&7)] = (ushort)f2bf(sg * h);
      } else {
        ubuf[(size_t)b*NU + (size_t)n*Uu + (o - Uu)] = (ushort)f2bf(sg);
      }
    }
  }
}

// ---------------- gconv2 output GEMM (MFMA), fused tanh + final gate ----------------
__global__ __launch_bounds__(256) void k_gemm2(const ushort* __restrict__ x0, const ushort* __restrict__ y1,
                                               const ushort* __restrict__ y2, const ushort* __restrict__ Wp,
                                               const float* __restrict__ bias, const float* __restrict__ hx,
                                               const ushort* __restrict__ ubuf, float* __restrict__ out) {
  __shared__ ushort Xs[64*XSTR];
  const int n = blockIdx.x, t = threadIdx.x;
  stage_xs(Xs, x0, y1, y2, n, t);
  const int w = t >> 6, l = t & 63;
  const int b0 = w * 16;
  f32x4 acc[4];
  for (int i = 0; i < 4; ++i) acc[i] = (f32x4){0.f,0.f,0.f,0.f};
  const int arow = b0 + (l & 15), koff0 = (l >> 4) * 8;
  for (int kk = 0; kk < 11; ++kk) {
    const short8 af = *(const short8*)&Xs[arow*XSTR + kk*32 + koff0];
    #pragma unroll
    for (int tt = 0; tt < 4; ++tt) {
      const short8 bf = *(const short8*)&Wp[(((size_t)tt*11 + kk)*64 + l)*8];
      acc[tt] = __builtin_amdgcn_mfma_f32_16x16x32_bf16(af, bf, acc[tt], 0, 0, 0);
    }
  }
  const int rg = (l >> 4) * 4;
  #pragma unroll
  for (int tt = 0; tt < 4; ++tt) {
    const int o = tt*16 + (l & 15);
    const float bs = bias[o];
    #pragma unroll
    for (int r = 0; r < 4; ++r) {
      const int b = b0 + rg + r;
      const float c = tanhf(acc[tt][r] + bs);
      const size_t ix = (size_t)b*NU + (size_t)n*Uu + o;
      const float u = __uint_as_float(((uint)ubuf[ix]) << 16);
      const float h = hx[ix];
      out[ix] = u*h + (1.0f - u)*c;
    }
  }
}

extern "C" void kernel_launch(void* const* d_in, const int* in_sizes, int n_in,
                              void* d_out, int out_size, void* d_ws, size_t ws_size,
                              hipStream_t stream) {
  const float* inp = (const float*)d_in[0];
  const float* hx  = (const float*)d_in[1];
  const float* sup = (const float*)d_in[2];
  const float* ruW = (const float*)d_in[3];
  const float* ruB = (const float*)d_in[4];
  const float* gW  = (const float*)d_in[5];
  const float* gB  = (const float*)d_in[6];
  float* out = (float*)d_out;

  // workspace: x0 | y1[2] | y2[2] | u | Wpk | ELL(row) | ELL(col) | rcnt  (~215 MB)
  ushort* x0   = (ushort*)d_ws;
  ushort* y1   = x0 + MATSZ;
  ushort* y2   = y1 + 2*MATSZ;
  ushort* ubuf = y2 + 2*MATSZ;
  ushort* Wp1  = ubuf + (size_t)Bb*NU;
  ushort* Wp2  = Wp1 + 45056;
  uint* pkv  = (uint*)(Wp2 + 22528);
  uint* pT   = pkv + (size_t)8192*ELLW;
  int*  rcnt = (int*)(pT + (size_t)8192*ELLW);

  k_fill<<<2048, 256, 0, stream>>>(sup, pkv, rcnt);
  k_tr<<<128, 256, 0, stream>>>(pkv, pT);
  k_wpack<<<264, 256, 0, stream>>>(ruW, gW, Wp1, Wp2);
  k_bx0<<<dim3(UNITS, 16), 256, 0, stream>>>(inp, hx, x0);

  // gconv1
  k_spmm<false><<<512, 1024, 0, stream>>>(x0, nullptr, y1, rcnt, pT);
  k_spmm<true ><<<512, 1024, 0, stream>>>(y1, x0,      y2, rcnt, pT);
  k_gemm1<<<Nn, 256, 0, stream>>>(x0, y1, y2, Wp1, ruB, hx, x0, ubuf);
  // gconv2 (x0 state slots now hold bf16(r*hx))
  k_spmm<false><<<512, 1024, 0, stream>>>(x0, nullptr, y1, rcnt, pT);
  k_spmm<true ><<<512, 1024, 0, stream>>>(y1, x0,      y2, rcnt, pT);
  k_gemm2<<<Nn, 256, 0, stream>>>(x0, y1, y2, Wp2, gB, hx, ubuf, out);
}